// Round 17
// baseline (53.785 us; speedup 1.0000x reference)
//
#include <hip/hip_runtime.h>
#include <math.h>

#define B_ 2
#define C_ 96
#define L_ 4096
#define N_ 16
#define R_ 6
#define K_ 4
#define D38 38
#define D40 40
#define CMROW 257   // col-major LDS row stride (elements)

typedef unsigned short ushort_t;
typedef unsigned int uint_t;

__device__ __forceinline__ uint_t bf16rtn(float f) {
    uint_t u = __float_as_uint(f);
    return (u + 0x7FFFu + ((u >> 16) & 1u)) >> 16;
}
__device__ __forceinline__ float bflo(uint_t p) { return __uint_as_float(p << 16); }
__device__ __forceinline__ float bfhi(uint_t p) { return __uint_as_float(p & 0xFFFF0000u); }

#define GETC(v, jj) ((jj) == 0 ? (v).x : (jj) == 1 ? (v).y : (jj) == 2 ? (v).z : (v).w)

// powers r^(8*hf+1) .. r^(8*hf+8) in ~12 muls + select
__device__ __forceinline__ void rpow8(float r, int hf, float* p) {
    float r2 = r * r, r3 = r2 * r, r4 = r2 * r2;
    p[0] = r;      p[1] = r2;     p[2] = r3;     p[3] = r4;
    p[4] = r4 * r; p[5] = r4 * r2; p[6] = r4 * r3; p[7] = r4 * r4;
    float sc = hf ? p[7] : 1.0f;
    #pragma unroll
    for (int e = 0; e < 8; ++e) p[e] *= sc;
}
__device__ __forceinline__ void unpack8(uint4 a, float* o) {
    o[0] = bflo(a.x); o[1] = bfhi(a.x); o[2] = bflo(a.y); o[3] = bfhi(a.y);
    o[4] = bflo(a.z); o[5] = bfhi(a.z); o[6] = bflo(a.w); o[7] = bfhi(a.w);
}

// ---------------------------------------------------------------------------
// Prep (unchanged): weight transpose, x->xT, fast-path flag.
// ---------------------------------------------------------------------------
__global__ __launch_bounds__(256) void prep_kernel(
    const float* __restrict__ w, const float* __restrict__ x,
    const float* __restrict__ A_log,
    float* __restrict__ wt, float* __restrict__ xT, int* __restrict__ flag)
{
    int blk = blockIdx.x;
    int tid = threadIdx.x;
    if (blk < 60) {
        int i = blk * 256 + tid;
        if (i < K_ * C_ * D40) {
            int k   = i / (C_ * D40);
            int rem = i % (C_ * D40);
            int cc  = rem / D40;
            int dd  = rem % D40;
            wt[i] = (dd < D38) ? w[((size_t)k * D38 + dd) * C_ + cc] : 0.f;
        }
    } else if (blk < 60 + B_ * C_) {
        __shared__ float t[64][65];
        int bc = blk - 60;
        const float* src = x  + (size_t)bc * L_;
        float*       dst = xT + (size_t)bc * L_;
        int r0  = tid >> 6;
        int col = tid & 63;
        #pragma unroll
        for (int rr = 0; rr < 16; ++rr) {
            int row = rr * 4 + r0;
            t[row][col] = src[row * 64 + col];
        }
        __syncthreads();
        #pragma unroll
        for (int rr = 0; rr < 16; ++rr) {
            int row = rr * 4 + r0;
            dst[row * 64 + col] = t[col][row];
        }
    } else {
        bool ok = true;
        for (int i = tid; i < K_ * C_ * N_; i += 256) {
            float a = __expf(A_log[i]);
            ok = ok && (fabsf(a - (float)((i & 15) + 1)) < 1e-3f);
        }
        __shared__ int sok[4];
        unsigned long long m = __ballot(ok);
        if ((tid & 63) == 0) sok[tid >> 6] = (m == 0xFFFFFFFFFFFFFFFFull) ? 1 : 0;
        __syncthreads();
        if (tid == 0) flag[0] = sok[0] & sok[1] & sok[2] & sok[3];
    }
}

// ---------------------------------------------------------------------------
// Kernel 1: projection (unchanged from R16 best). Direct coalesced x reads,
// scalar weight loads, r-only output, bf16 B/C chunk-transposed.
// ---------------------------------------------------------------------------
__global__ __launch_bounds__(512) void proj_kernel(
    const float* __restrict__ x, const float* __restrict__ xT,
    const float* __restrict__ wt, const float* __restrict__ dpw,
    const float* __restrict__ dpb,
    float* __restrict__ ws_r,
    ushort_t* __restrict__ ws_Bm, ushort_t* __restrict__ ws_Cm)
{
    __shared__ float T2[2][64][41];      // 21 KB

    int blk  = blockIdx.x;               // lt*8 + bk
    int bk   = blk & 7;
    int lt   = blk >> 3;
    int k    = bk & 3;
    int b    = bk >> 2;

    int tid  = threadIdx.x;
    int l0   = tid & 63;
    int dq_u = __builtin_amdgcn_readfirstlane((tid >> 6) & 3);
    int ch_u = __builtin_amdgcn_readfirstlane(tid >> 8);
    int base = dq_u * 10;                // cols 38,39 zero-padded

    int l = lt * 64 + l0;
    int m = (k >= 2) ? (L_ - 1 - l) : l;
    const float* srcb = ((k & 1) ? xT : x) + (size_t)b * C_ * L_;

    const float* wk = wt + k * C_ * D40 + base;
    float acc[10];
    #pragma unroll
    for (int t = 0; t < 10; ++t) acc[t] = 0.f;
    int c0 = ch_u * 48;
    #pragma unroll 4
    for (int cc = 0; cc < 48; ++cc) {
        int c = c0 + cc;
        float xv = srcb[(size_t)c * L_ + m];   // coalesced global read
        const float* wc = wk + c * D40;        // uniform -> s_load
        #pragma unroll
        for (int t = 0; t < 10; ++t) acc[t] = fmaf(xv, wc[t], acc[t]);
    }
    #pragma unroll
    for (int t = 0; t < 10; ++t) T2[ch_u][l0][base + t] = acc[t];
    __syncthreads();

    // ---- B/C bf16 stores, chunk-transposed: uint2 idx = ((bk*16+j)*256+g)*4+q
    {
        int lq = tid >> 3, sub = tid & 7;
        int buf = sub >> 2, q = sub & 3;
        int col = R_ + buf * 16 + 4 * q;
        float v0 = T2[0][lq][col]     + T2[1][lq][col];
        float v1 = T2[0][lq][col + 1] + T2[1][lq][col + 1];
        float v2 = T2[0][lq][col + 2] + T2[1][lq][col + 2];
        float v3 = T2[0][lq][col + 3] + T2[1][lq][col + 3];
        uint_t p0 = bf16rtn(v0) | (bf16rtn(v1) << 16);
        uint_t p1 = bf16rtn(v2) | (bf16rtn(v3) << 16);
        int ll = lt * 64 + lq;
        int j = ll & 15, g = ll >> 4;
        size_t o = (size_t)bk * 16384 + j * 1024 + g * 4 + q;
        uint2* dst = (uint2*)(buf ? ws_Cm : ws_Bm);
        dst[o] = make_uint2(p0, p1);
    }

    // ---- delta projection; store only r = 1/(1+e^s) = exp(-softplus(s))
    float ar[R_];
    #pragma unroll
    for (int r = 0; r < R_; ++r) ar[r] = T2[0][l0][r] + T2[1][l0][r];
    float* rlt = ws_r + (size_t)bk * C_ * L_ + lt * 64 + l0;
    int cq_u = ch_u * 4 + dq_u;
    #pragma unroll 2
    for (int cc = 0; cc < 12; ++cc) {
        int c = cc * 8 + cq_u;
        const float* dc = dpw + (k * C_ + c) * R_;   // uniform -> s_load
        float s = dpb[k * C_ + c];
        #pragma unroll
        for (int r = 0; r < R_; ++r) s = fmaf(ar[r], dc[r], s);
        float em  = __expf(-fabsf(s));
        float inv = 1.0f / (1.0f + em);
        float rr  = (s > 0.f) ? (em * inv) : inv;    // exp(-softplus(s))
        rlt[(size_t)c * L_] = rr;
    }
}

// ---------------------------------------------------------------------------
// Kernel 2: selective scan, 512 threads per channel. Thread (g, hf): chunk g
// of 16 l's x 8 states (n in [8hf, 8hf+8)). Halved per-thread registers ->
// target 24-32 waves/CU (was 16). y combined across the pair via shfl_xor.
// ---------------------------------------------------------------------------
__global__ __launch_bounds__(512, 6) void scan_kernel(
    const float* __restrict__ ws_r,
    const float* __restrict__ x, const float* __restrict__ xT,
    const ushort_t* __restrict__ ws_Bm, const ushort_t* __restrict__ ws_Cm,
    const float* __restrict__ A_log, const float* __restrict__ Ds,
    const int* __restrict__ flagp, float* __restrict__ out)
{
    __shared__ float s_u[16 * CMROW];    // 16.4 KB, [j][g] col-major
    __shared__ float s_r[16 * CMROW];    // 16.4 KB
    __shared__ float s_wR[8];
    __shared__ float s_wB[8][N_];

    int blk = blockIdx.x;                // c*8 + bk (XCD swizzle)
    int bk  = blk & 7;
    int c   = blk >> 3;
    int k   = bk & 3;
    int b   = bk >> 2;
    int chn = bk * C_ + c;
    int d   = k * C_ + c;

    int t    = threadIdx.x;
    int hf   = t & 1;                    // state half
    int g    = t >> 1;                   // chunk 0..255
    int w    = t >> 6;                   // wave 0..7
    int lane = t & 63;
    int i    = lane >> 1;                // chunk-in-wave 0..31

    int fast = flagp[0];
    float A8[8];
    if (!fast) {
        #pragma unroll
        for (int e = 0; e < 8; ++e)
            A8[e] = -__expf(A_log[(size_t)d * N_ + 8 * hf + e]);
    }

    // ---- stage u and r into col-major LDS (coalesced global reads)
    const float* usrc = ((k & 1) ? xT : x) + ((size_t)b * C_ + c) * L_;
    {
        const float* rp = ws_r + (size_t)chn * L_;
        #pragma unroll
        for (int it = 0; it < 2; ++it) {
            int e = t * 4 + it * 2048;   // scan position l = e..e+3
            float4 vr = *(const float4*)(rp + e);
            float4 vu;
            if (k < 2) {
                vu = *(const float4*)(usrc + e);
            } else {
                float4 t4 = *(const float4*)(usrc + (L_ - 4 - e));
                vu = make_float4(t4.w, t4.z, t4.y, t4.x);
            }
            int gg = e >> 4, j0 = e & 15;
            #pragma unroll
            for (int jj = 0; jj < 4; ++jj) {
                s_u[(j0 + jj) * CMROW + gg] = GETC(vu, jj);
                s_r[(j0 + jj) * CMROW + gg] = GETC(vr, jj);
            }
        }
    }
    __syncthreads();

    const uint4* B4 = (const uint4*)ws_Bm;   // 8 bf16 per uint4
    const uint4* C4 = (const uint4*)ws_Cm;
    int ib = bk * 8192 + g * 2 + hf;         // + j*512 per j (uint4 units)

    float Rc = 1.f, Sc = 0.f;
    float Bc[8];
    #pragma unroll
    for (int e = 0; e < 8; ++e) Bc[e] = 0.f;

    // ---- pass 1: chunk composite (8 states)
    if (fast) {
        #pragma unroll 4
        for (int j = 0; j < 16; ++j) {
            float r  = s_r[j * CMROW + g];
            float u  = s_u[j * CMROW + g];
            float dl = -__logf(fmaxf(r, 1e-30f));
            float du = dl * u;
            uint4 bv = B4[ib + j * 512];
            float bb[8]; unpack8(bv, bb);
            float p[8]; rpow8(r, hf, p);
            #pragma unroll
            for (int e = 0; e < 8; ++e)
                Bc[e] = fmaf(p[e], Bc[e], du * bb[e]);
            Rc *= r;
        }
    } else {
        #pragma unroll 1
        for (int j = 0; j < 16; ++j) {
            float r  = s_r[j * CMROW + g];
            float u  = s_u[j * CMROW + g];
            float dl = -__logf(fmaxf(r, 1e-30f));
            float du = dl * u;
            uint4 bv = B4[ib + j * 512];
            float bb[8]; unpack8(bv, bb);
            #pragma unroll
            for (int e = 0; e < 8; ++e) {
                float a = __expf(dl * A8[e]);
                Bc[e] = fmaf(a, Bc[e], du * bb[e]);
            }
            Sc += dl;
        }
    }

    // ---- intra-wave butterfly scan (32 chunks per wave, stride-2 lanes)
    if (fast) {
        #pragma unroll
        for (int s = 1; s < 32; s <<= 1) {
            float pR = __shfl_up(Rc, 2 * s, 64);
            float pB[8];
            #pragma unroll
            for (int e = 0; e < 8; ++e) pB[e] = __shfl_up(Bc[e], 2 * s, 64);
            if (i >= s) {
                float p[8]; rpow8(Rc, hf, p);
                #pragma unroll
                for (int e = 0; e < 8; ++e) Bc[e] = fmaf(p[e], pB[e], Bc[e]);
                Rc *= pR;
            }
        }
    } else {
        #pragma unroll 1
        for (int s = 1; s < 32; s <<= 1) {
            float pS = __shfl_up(Sc, 2 * s, 64);
            float pB[8];
            #pragma unroll
            for (int e = 0; e < 8; ++e) pB[e] = __shfl_up(Bc[e], 2 * s, 64);
            if (i >= s) {
                #pragma unroll
                for (int e = 0; e < 8; ++e) {
                    float a = __expf(A8[e] * Sc);
                    Bc[e] = fmaf(a, pB[e], Bc[e]);
                }
                Sc += pS;
            }
        }
    }

    // ---- inter-wave combine (8 waves)
    if (i == 31) {
        if (hf == 0) s_wR[w] = fast ? Rc : Sc;
        #pragma unroll
        for (int e = 0; e < 8; ++e) s_wB[w][8 * hf + e] = Bc[e];
    }
    __syncthreads();

    float h[8];
    #pragma unroll
    for (int e = 0; e < 8; ++e) h[e] = 0.f;
    if (fast) {
        #pragma unroll 1
        for (int v = 0; v < w; ++v) {
            float p[8]; rpow8(s_wR[v], hf, p);
            #pragma unroll
            for (int e = 0; e < 8; ++e) h[e] = fmaf(p[e], h[e], s_wB[v][8 * hf + e]);
        }
        float pR = __shfl_up(Rc, 2, 64);
        float pB[8];
        #pragma unroll
        for (int e = 0; e < 8; ++e) pB[e] = __shfl_up(Bc[e], 2, 64);
        if (i > 0) {
            float p[8]; rpow8(pR, hf, p);
            #pragma unroll
            for (int e = 0; e < 8; ++e) h[e] = fmaf(p[e], h[e], pB[e]);
        }
    } else {
        #pragma unroll 1
        for (int v = 0; v < w; ++v) {
            float Sv = s_wR[v];
            #pragma unroll
            for (int e = 0; e < 8; ++e) {
                float a = __expf(A8[e] * Sv);
                h[e] = fmaf(a, h[e], s_wB[v][8 * hf + e]);
            }
        }
        float pS = __shfl_up(Sc, 2, 64);
        float pB[8];
        #pragma unroll
        for (int e = 0; e < 8; ++e) pB[e] = __shfl_up(Bc[e], 2, 64);
        if (i > 0) {
            #pragma unroll
            for (int e = 0; e < 8; ++e) {
                float a = __expf(A8[e] * pS);
                h[e] = fmaf(a, h[e], pB[e]);
            }
        }
    }

    // ---- pass 2: apply + output (pair-reduced y via shfl_xor 1)
    float Dd = Ds[d];
    int osel = (k == 0) ? 0 : (k == 2) ? 1 : (k == 1) ? 2 : 3;
    float* ob = out + ((size_t)osel * B_ + b) * ((size_t)C_ * L_) + (size_t)c * L_;
    int gl = g * 16;

    if (fast) {
        #pragma unroll
        for (int jq = 0; jq < 4; ++jq) {
            float yb0, yb1, yb2, yb3;
            #pragma unroll
            for (int jj = 0; jj < 4; ++jj) {
                int j = jq * 4 + jj;
                float r  = s_r[j * CMROW + g];
                float u  = s_u[j * CMROW + g];
                float dl = -__logf(fmaxf(r, 1e-30f));
                float du = dl * u;
                uint4 bv = B4[ib + j * 512];
                uint4 cv = C4[ib + j * 512];
                float bb[8]; unpack8(bv, bb);
                float cc[8]; unpack8(cv, cc);
                float p[8]; rpow8(r, hf, p);
                float y = 0.f;
                #pragma unroll
                for (int e = 0; e < 8; ++e) {
                    h[e] = fmaf(p[e], h[e], du * bb[e]);
                    y = fmaf(h[e], cc[e], y);
                }
                y += __shfl_xor(y, 1, 64);
                y = fmaf(Dd, u, y);
                if (jj == 0) yb0 = y; else if (jj == 1) yb1 = y;
                else if (jj == 2) yb2 = y; else yb3 = y;
                if ((k & 1) && hf == 0) {
                    int l = gl + j;
                    int mm = (k == 1) ? l : (L_ - 1 - l);
                    ob[((mm & 63) << 6) | (mm >> 6)] = y;
                }
            }
            if (!(k & 1) && hf == 0) {
                if (k == 0) {
                    *(float4*)(ob + gl + jq * 4) = make_float4(yb0, yb1, yb2, yb3);
                } else {
                    *(float4*)(ob + (L_ - 4 - gl - jq * 4)) =
                        make_float4(yb3, yb2, yb1, yb0);
                }
            }
        }
    } else {
        #pragma unroll 1
        for (int j = 0; j < 16; ++j) {
            float r  = s_r[j * CMROW + g];
            float u  = s_u[j * CMROW + g];
            float dl = -__logf(fmaxf(r, 1e-30f));
            float du = dl * u;
            int l = gl + j;
            uint4 bv = B4[ib + j * 512];
            uint4 cv = C4[ib + j * 512];
            float bb[8]; unpack8(bv, bb);
            float cc[8]; unpack8(cv, cc);
            float y = 0.f;
            #pragma unroll
            for (int e = 0; e < 8; ++e) {
                float a = __expf(dl * A8[e]);
                h[e] = fmaf(a, h[e], du * bb[e]);
                y = fmaf(h[e], cc[e], y);
            }
            y += __shfl_xor(y, 1, 64);
            if (hf == 0) {
                y = fmaf(Dd, u, y);
                int idx;
                if (k == 0)      idx = l;
                else if (k == 2) idx = L_ - 1 - l;
                else if (k == 1) idx = ((l & 63) << 6) | (l >> 6);
                else { int mm = L_ - 1 - l; idx = ((mm & 63) << 6) | (mm >> 6); }
                ob[idx] = y;
            }
        }
    }
}

// ---------------------------------------------------------------------------
extern "C" void kernel_launch(void* const* d_in, const int* in_sizes, int n_in,
                              void* d_out, int out_size, void* d_ws, size_t ws_size,
                              hipStream_t stream) {
    const float* x     = (const float*)d_in[0];
    const float* xpw   = (const float*)d_in[1];
    const float* dpw   = (const float*)d_in[2];
    const float* dpb   = (const float*)d_in[3];
    const float* A_log = (const float*)d_in[4];
    const float* Ds    = (const float*)d_in[5];
    float* out = (float*)d_out;

    float* ws = (float*)d_ws;
    const size_t dL  = (size_t)B_ * K_ * C_ * L_;   // 3,145,728 floats
    const size_t bcL = (size_t)B_ * K_ * L_ * N_;   //   524,288 bf16 elements
    const size_t xL  = (size_t)B_ * C_ * L_;        //   786,432 floats
    float*    ws_r  = ws;                            // dL floats
    ushort_t* ws_Bm = (ushort_t*)(ws + dL);          // bcL ushorts
    ushort_t* ws_Cm = ws_Bm + bcL;                   // bcL ushorts
    float*    ws_xT = ws + dL + bcL;                 // xL floats
    float*    ws_Wt = ws_xT + xL;                    // K*C*40 floats
    int*      ws_fl = (int*)(ws_Wt + (size_t)K_ * C_ * D40);

    prep_kernel<<<60 + B_ * C_ + 1, 256, 0, stream>>>(
        xpw, x, A_log, ws_Wt, ws_xT, ws_fl);
    proj_kernel<<<B_ * K_ * (L_ / 64), 512, 0, stream>>>(
        x, ws_xT, ws_Wt, dpw, dpb, ws_r, ws_Bm, ws_Cm);
    scan_kernel<<<B_ * K_ * C_, 512, 0, stream>>>(
        ws_r, x, ws_xT, ws_Bm, ws_Cm, A_log, Ds, ws_fl, out);
}

// Round 18
// 50.851 us; speedup vs baseline: 1.0577x; 1.0577x over previous
//
#include <hip/hip_runtime.h>
#include <math.h>

#define B_ 2
#define C_ 96
#define L_ 4096
#define N_ 16
#define R_ 6
#define K_ 4
#define D38 38
#define D40 40
#define CMROW 257   // col-major LDS row stride (elements)

typedef unsigned short ushort_t;
typedef unsigned int uint_t;

__device__ __forceinline__ uint_t bf16rtn(float f) {
    uint_t u = __float_as_uint(f);
    return (u + 0x7FFFu + ((u >> 16) & 1u)) >> 16;
}
__device__ __forceinline__ float bflo(uint_t p) { return __uint_as_float(p << 16); }
__device__ __forceinline__ float bfhi(uint_t p) { return __uint_as_float(p & 0xFFFF0000u); }

#define GETC(v, jj) ((jj) == 0 ? (v).x : (jj) == 1 ? (v).y : (jj) == 2 ? (v).z : (v).w)

// powers r^1..r^16 in 15 muls
__device__ __forceinline__ void rpow16(float r, float* p) {
    float r2 = r * r, r4 = r2 * r2, r8 = r4 * r4;
    p[0] = r;        p[1] = r2;       p[2] = r2 * r;   p[3] = r4;
    p[4] = r4 * r;   p[5] = r4 * r2;  p[6] = r4 * p[2]; p[7] = r8;
    p[8] = r8 * r;   p[9] = r8 * r2;  p[10] = r8 * p[2]; p[11] = r8 * r4;
    p[12] = r8 * p[4]; p[13] = r8 * p[5]; p[14] = r8 * p[6]; p[15] = r8 * r8;
}
__device__ __forceinline__ void unpack16(uint4 a, uint4 b, float* o) {
    o[0] = bflo(a.x);  o[1] = bfhi(a.x);  o[2] = bflo(a.y);  o[3] = bfhi(a.y);
    o[4] = bflo(a.z);  o[5] = bfhi(a.z);  o[6] = bflo(a.w);  o[7] = bfhi(a.w);
    o[8] = bflo(b.x);  o[9] = bfhi(b.x);  o[10] = bflo(b.y); o[11] = bfhi(b.y);
    o[12] = bflo(b.z); o[13] = bfhi(b.z); o[14] = bflo(b.w); o[15] = bfhi(b.w);
}

// ---------------------------------------------------------------------------
// Prep: weight transpose, x->xT, fast-path flag.
// ---------------------------------------------------------------------------
__global__ __launch_bounds__(256) void prep_kernel(
    const float* __restrict__ w, const float* __restrict__ x,
    const float* __restrict__ A_log,
    float* __restrict__ wt, float* __restrict__ xT, int* __restrict__ flag)
{
    int blk = blockIdx.x;
    int tid = threadIdx.x;
    if (blk < 60) {
        int i = blk * 256 + tid;
        if (i < K_ * C_ * D40) {
            int k   = i / (C_ * D40);
            int rem = i % (C_ * D40);
            int cc  = rem / D40;
            int dd  = rem % D40;
            wt[i] = (dd < D38) ? w[((size_t)k * D38 + dd) * C_ + cc] : 0.f;
        }
    } else if (blk < 60 + B_ * C_) {
        __shared__ float t[64][65];
        int bc = blk - 60;
        const float* src = x  + (size_t)bc * L_;
        float*       dst = xT + (size_t)bc * L_;
        int r0  = tid >> 6;
        int col = tid & 63;
        #pragma unroll
        for (int rr = 0; rr < 16; ++rr) {
            int row = rr * 4 + r0;
            t[row][col] = src[row * 64 + col];
        }
        __syncthreads();
        #pragma unroll
        for (int rr = 0; rr < 16; ++rr) {
            int row = rr * 4 + r0;
            dst[row * 64 + col] = t[col][row];
        }
    } else {
        bool ok = true;
        for (int i = tid; i < K_ * C_ * N_; i += 256) {
            float a = __expf(A_log[i]);
            ok = ok && (fabsf(a - (float)((i & 15) + 1)) < 1e-3f);
        }
        __shared__ int sok[4];
        unsigned long long m = __ballot(ok);
        if ((tid & 63) == 0) sok[tid >> 6] = (m == 0xFFFFFFFFFFFFFFFFull) ? 1 : 0;
        __syncthreads();
        if (tid == 0) flag[0] = sok[0] & sok[1] & sok[2] & sok[3];
    }
}

// ---------------------------------------------------------------------------
// Kernel 1: projection (R16 best). Direct coalesced x reads, scalar weight
// loads, r-only output, bf16 B/C chunk-transposed. LDS = T2 only (21 KB).
// XCD swizzle: blockIdx = lt*8 + bk.
// ---------------------------------------------------------------------------
__global__ __launch_bounds__(512) void proj_kernel(
    const float* __restrict__ x, const float* __restrict__ xT,
    const float* __restrict__ wt, const float* __restrict__ dpw,
    const float* __restrict__ dpb,
    float* __restrict__ ws_r,
    ushort_t* __restrict__ ws_Bm, ushort_t* __restrict__ ws_Cm)
{
    __shared__ float T2[2][64][41];      // 21 KB

    int blk  = blockIdx.x;               // lt*8 + bk
    int bk   = blk & 7;
    int lt   = blk >> 3;
    int k    = bk & 3;
    int b    = bk >> 2;

    int tid  = threadIdx.x;
    int l0   = tid & 63;
    int dq_u = __builtin_amdgcn_readfirstlane((tid >> 6) & 3);
    int ch_u = __builtin_amdgcn_readfirstlane(tid >> 8);
    int base = dq_u * 10;                // cols 38,39 zero-padded

    int l = lt * 64 + l0;
    int m = (k >= 2) ? (L_ - 1 - l) : l; // coalesced (maybe reversed) per c
    const float* srcb = ((k & 1) ? xT : x) + (size_t)b * C_ * L_;

    const float* wk = wt + k * C_ * D40 + base;
    float acc[10];
    #pragma unroll
    for (int t = 0; t < 10; ++t) acc[t] = 0.f;
    int c0 = ch_u * 48;
    #pragma unroll 4
    for (int cc = 0; cc < 48; ++cc) {
        int c = c0 + cc;
        float xv = srcb[(size_t)c * L_ + m];   // coalesced global read
        const float* wc = wk + c * D40;        // uniform -> s_load
        #pragma unroll
        for (int t = 0; t < 10; ++t) acc[t] = fmaf(xv, wc[t], acc[t]);
    }
    #pragma unroll
    for (int t = 0; t < 10; ++t) T2[ch_u][l0][base + t] = acc[t];
    __syncthreads();

    // ---- B/C bf16 stores, chunk-transposed: uint2 idx = ((bk*16+j)*256+g)*4+q
    {
        int lq = tid >> 3, sub = tid & 7;
        int buf = sub >> 2, q = sub & 3;
        int col = R_ + buf * 16 + 4 * q;
        float v0 = T2[0][lq][col]     + T2[1][lq][col];
        float v1 = T2[0][lq][col + 1] + T2[1][lq][col + 1];
        float v2 = T2[0][lq][col + 2] + T2[1][lq][col + 2];
        float v3 = T2[0][lq][col + 3] + T2[1][lq][col + 3];
        uint_t p0 = bf16rtn(v0) | (bf16rtn(v1) << 16);
        uint_t p1 = bf16rtn(v2) | (bf16rtn(v3) << 16);
        int ll = lt * 64 + lq;
        int j = ll & 15, g = ll >> 4;
        size_t o = (size_t)bk * 16384 + j * 1024 + g * 4 + q;
        uint2* dst = (uint2*)(buf ? ws_Cm : ws_Bm);
        dst[o] = make_uint2(p0, p1);
    }

    // ---- delta projection; store only r = 1/(1+e^s) = exp(-softplus(s))
    float ar[R_];
    #pragma unroll
    for (int r = 0; r < R_; ++r) ar[r] = T2[0][l0][r] + T2[1][l0][r];
    float* rlt = ws_r + (size_t)bk * C_ * L_ + lt * 64 + l0;
    int cq_u = ch_u * 4 + dq_u;
    #pragma unroll 2
    for (int cc = 0; cc < 12; ++cc) {
        int c = cc * 8 + cq_u;
        const float* dc = dpw + (k * C_ + c) * R_;   // uniform -> s_load
        float s = dpb[k * C_ + c];
        #pragma unroll
        for (int r = 0; r < R_; ++r) s = fmaf(ar[r], dc[r], s);
        float em  = __expf(-fabsf(s));
        float inv = 1.0f / (1.0f + em);
        float rr  = (s > 0.f) ? (em * inv) : inv;    // exp(-softplus(s))
        rlt[(size_t)c * L_] = rr;
    }
}

// ---------------------------------------------------------------------------
// Kernel 2: selective scan (R16 best), 256 threads per channel; thread g =
// chunk of 16 l's x all 16 states. delta = -ln(r); u f32 in LDS.
// ---------------------------------------------------------------------------
__global__ __launch_bounds__(256) void scan_kernel(
    const float* __restrict__ ws_r,
    const float* __restrict__ x, const float* __restrict__ xT,
    const ushort_t* __restrict__ ws_Bm, const ushort_t* __restrict__ ws_Cm,
    const float* __restrict__ A_log, const float* __restrict__ Ds,
    const int* __restrict__ flagp, float* __restrict__ out)
{
    __shared__ float s_u[16 * CMROW];    // 16.4 KB, [j][g] col-major
    __shared__ float s_r[16 * CMROW];    // 16.4 KB
    __shared__ float s_wR[4];
    __shared__ float s_wB[4][N_];

    int blk = blockIdx.x;                // c*8 + bk (XCD swizzle)
    int bk  = blk & 7;
    int c   = blk >> 3;
    int k   = bk & 3;
    int b   = bk >> 2;
    int chn = bk * C_ + c;
    int d   = k * C_ + c;

    int t    = threadIdx.x;              // chunk id g = t
    int w    = t >> 6;
    int lane = t & 63;

    int fast = flagp[0];
    float A16[16];
    if (!fast) {
        #pragma unroll
        for (int n = 0; n < 16; ++n)
            A16[n] = -__expf(A_log[(size_t)d * N_ + n]);
    }

    // ---- stage u and r into col-major LDS (coalesced global reads)
    const float* usrc = ((k & 1) ? xT : x) + ((size_t)b * C_ + c) * L_;
    {
        const float* rp = ws_r + (size_t)chn * L_;
        #pragma unroll
        for (int it = 0; it < 4; ++it) {
            int e = t * 4 + it * 1024;   // scan position l = e..e+3
            float4 vr = *(const float4*)(rp + e);
            float4 vu;
            if (k < 2) {
                vu = *(const float4*)(usrc + e);
            } else {
                float4 t4 = *(const float4*)(usrc + (L_ - 4 - e));
                vu = make_float4(t4.w, t4.z, t4.y, t4.x);
            }
            int gg = e >> 4, j0 = e & 15;
            #pragma unroll
            for (int jj = 0; jj < 4; ++jj) {
                s_u[(j0 + jj) * CMROW + gg] = GETC(vu, jj);
                s_r[(j0 + jj) * CMROW + gg] = GETC(vr, jj);
            }
        }
    }
    __syncthreads();

    int g = t;
    const uint4* B4 = (const uint4*)ws_Bm;   // 8 bf16 per uint4
    const uint4* C4 = (const uint4*)ws_Cm;
    int ib = bk * 8192 + g * 2;              // + j*512 per j (uint4 units)

    float Rc = 1.f, Sc = 0.f;
    float Bc[16];
    #pragma unroll
    for (int n = 0; n < 16; ++n) Bc[n] = 0.f;

    // ---- pass 1: chunk composite
    if (fast) {
        #pragma unroll 4
        for (int j = 0; j < 16; ++j) {
            float r  = s_r[j * CMROW + g];
            float u  = s_u[j * CMROW + g];
            float dl = -__logf(fmaxf(r, 1e-30f));
            float du = dl * u;
            uint4 b0 = B4[ib + j * 512];
            uint4 b1 = B4[ib + j * 512 + 1];
            float bb[16]; unpack16(b0, b1, bb);
            float p[16]; rpow16(r, p);
            #pragma unroll
            for (int n = 0; n < 16; ++n)
                Bc[n] = fmaf(p[n], Bc[n], du * bb[n]);
            Rc *= r;
        }
    } else {
        #pragma unroll 1
        for (int j = 0; j < 16; ++j) {
            float r  = s_r[j * CMROW + g];
            float u  = s_u[j * CMROW + g];
            float dl = -__logf(fmaxf(r, 1e-30f));
            float du = dl * u;
            uint4 b0 = B4[ib + j * 512];
            uint4 b1 = B4[ib + j * 512 + 1];
            float bb[16]; unpack16(b0, b1, bb);
            #pragma unroll
            for (int n = 0; n < 16; ++n) {
                float a = __expf(dl * A16[n]);
                Bc[n] = fmaf(a, Bc[n], du * bb[n]);
            }
            Sc += dl;
        }
    }

    // ---- intra-wave butterfly scan (64 chunks per wave)
    if (fast) {
        #pragma unroll
        for (int s = 1; s < 64; s <<= 1) {
            float pR = __shfl_up(Rc, s, 64);
            float pB[16];
            #pragma unroll
            for (int n = 0; n < 16; ++n) pB[n] = __shfl_up(Bc[n], s, 64);
            if (lane >= s) {
                float p[16]; rpow16(Rc, p);
                #pragma unroll
                for (int n = 0; n < 16; ++n) Bc[n] = fmaf(p[n], pB[n], Bc[n]);
                Rc *= pR;
            }
        }
    } else {
        #pragma unroll 1
        for (int s = 1; s < 64; s <<= 1) {
            float pS = __shfl_up(Sc, s, 64);
            float pB[16];
            #pragma unroll
            for (int n = 0; n < 16; ++n) pB[n] = __shfl_up(Bc[n], s, 64);
            if (lane >= s) {
                #pragma unroll
                for (int n = 0; n < 16; ++n) {
                    float a = __expf(A16[n] * Sc);
                    Bc[n] = fmaf(a, pB[n], Bc[n]);
                }
                Sc += pS;
            }
        }
    }

    // ---- inter-wave combine (4 waves)
    if (lane == 63) {
        s_wR[w] = fast ? Rc : Sc;
        #pragma unroll
        for (int n = 0; n < 16; ++n) s_wB[w][n] = Bc[n];
    }
    __syncthreads();

    float h[16];
    #pragma unroll
    for (int n = 0; n < 16; ++n) h[n] = 0.f;
    if (fast) {
        for (int v = 0; v < w; ++v) {
            float p[16]; rpow16(s_wR[v], p);
            #pragma unroll
            for (int n = 0; n < 16; ++n) h[n] = fmaf(p[n], h[n], s_wB[v][n]);
        }
        float pR = __shfl_up(Rc, 1, 64);
        float pB[16];
        #pragma unroll
        for (int n = 0; n < 16; ++n) pB[n] = __shfl_up(Bc[n], 1, 64);
        if (lane > 0) {
            float p[16]; rpow16(pR, p);
            #pragma unroll
            for (int n = 0; n < 16; ++n) h[n] = fmaf(p[n], h[n], pB[n]);
        }
    } else {
        #pragma unroll 1
        for (int v = 0; v < w; ++v) {
            float Sv = s_wR[v];
            #pragma unroll
            for (int n = 0; n < 16; ++n) {
                float a = __expf(A16[n] * Sv);
                h[n] = fmaf(a, h[n], s_wB[v][n]);
            }
        }
        float pS = __shfl_up(Sc, 1, 64);
        float pB[16];
        #pragma unroll
        for (int n = 0; n < 16; ++n) pB[n] = __shfl_up(Bc[n], 1, 64);
        if (lane > 0) {
            #pragma unroll
            for (int n = 0; n < 16; ++n) {
                float a = __expf(A16[n] * pS);
                h[n] = fmaf(a, h[n], pB[n]);
            }
        }
    }

    // ---- pass 2: apply + output
    float Dd = Ds[d];
    int osel = (k == 0) ? 0 : (k == 2) ? 1 : (k == 1) ? 2 : 3;
    float* ob = out + ((size_t)osel * B_ + b) * ((size_t)C_ * L_) + (size_t)c * L_;
    int gl = g * 16;

    if (fast) {
        #pragma unroll
        for (int jq = 0; jq < 4; ++jq) {
            float yb0, yb1, yb2, yb3;
            #pragma unroll
            for (int jj = 0; jj < 4; ++jj) {
                int j = jq * 4 + jj;
                float r  = s_r[j * CMROW + g];
                float u  = s_u[j * CMROW + g];
                float dl = -__logf(fmaxf(r, 1e-30f));
                float du = dl * u;
                uint4 b0 = B4[ib + j * 512];
                uint4 b1 = B4[ib + j * 512 + 1];
                uint4 c0 = C4[ib + j * 512];
                uint4 c1 = C4[ib + j * 512 + 1];
                float bb[16]; unpack16(b0, b1, bb);
                float cc[16]; unpack16(c0, c1, cc);
                float p[16]; rpow16(r, p);
                float y = 0.f;
                #pragma unroll
                for (int n = 0; n < 16; ++n) {
                    h[n] = fmaf(p[n], h[n], du * bb[n]);
                    y = fmaf(h[n], cc[n], y);
                }
                y = fmaf(Dd, u, y);
                if (jj == 0) yb0 = y; else if (jj == 1) yb1 = y;
                else if (jj == 2) yb2 = y; else yb3 = y;
                if (k & 1) {
                    int l = gl + j;
                    int mm = (k == 1) ? l : (L_ - 1 - l);
                    ob[((mm & 63) << 6) | (mm >> 6)] = y;
                }
            }
            if (!(k & 1)) {
                if (k == 0) {
                    *(float4*)(ob + gl + jq * 4) = make_float4(yb0, yb1, yb2, yb3);
                } else {
                    *(float4*)(ob + (L_ - 4 - gl - jq * 4)) =
                        make_float4(yb3, yb2, yb1, yb0);
                }
            }
        }
    } else {
        #pragma unroll 1
        for (int j = 0; j < 16; ++j) {
            float r  = s_r[j * CMROW + g];
            float u  = s_u[j * CMROW + g];
            float dl = -__logf(fmaxf(r, 1e-30f));
            float du = dl * u;
            int l = gl + j;
            uint4 b0 = B4[ib + j * 512];
            uint4 b1 = B4[ib + j * 512 + 1];
            uint4 c0 = C4[ib + j * 512];
            uint4 c1 = C4[ib + j * 512 + 1];
            float bb[16]; unpack16(b0, b1, bb);
            float cc[16]; unpack16(c0, c1, cc);
            float y = 0.f;
            #pragma unroll
            for (int n = 0; n < 16; ++n) {
                float a = __expf(dl * A16[n]);
                h[n] = fmaf(a, h[n], du * bb[n]);
                y = fmaf(h[n], cc[n], y);
            }
            y = fmaf(Dd, u, y);
            int idx;
            if (k == 0)      idx = l;
            else if (k == 2) idx = L_ - 1 - l;
            else if (k == 1) idx = ((l & 63) << 6) | (l >> 6);
            else { int mm = L_ - 1 - l; idx = ((mm & 63) << 6) | (mm >> 6); }
            ob[idx] = y;
        }
    }
}

// ---------------------------------------------------------------------------
extern "C" void kernel_launch(void* const* d_in, const int* in_sizes, int n_in,
                              void* d_out, int out_size, void* d_ws, size_t ws_size,
                              hipStream_t stream) {
    const float* x     = (const float*)d_in[0];
    const float* xpw   = (const float*)d_in[1];
    const float* dpw   = (const float*)d_in[2];
    const float* dpb   = (const float*)d_in[3];
    const float* A_log = (const float*)d_in[4];
    const float* Ds    = (const float*)d_in[5];
    float* out = (float*)d_out;

    float* ws = (float*)d_ws;
    const size_t dL  = (size_t)B_ * K_ * C_ * L_;   // 3,145,728 floats
    const size_t bcL = (size_t)B_ * K_ * L_ * N_;   //   524,288 bf16 elements
    const size_t xL  = (size_t)B_ * C_ * L_;        //   786,432 floats
    float*    ws_r  = ws;                            // dL floats
    ushort_t* ws_Bm = (ushort_t*)(ws + dL);          // bcL ushorts
    ushort_t* ws_Cm = ws_Bm + bcL;                   // bcL ushorts
    float*    ws_xT = ws + dL + bcL;                 // xL floats
    float*    ws_Wt = ws_xT + xL;                    // K*C*40 floats
    int*      ws_fl = (int*)(ws_Wt + (size_t)K_ * C_ * D40);

    prep_kernel<<<60 + B_ * C_ + 1, 256, 0, stream>>>(
        xpw, x, A_log, ws_Wt, ws_xT, ws_fl);
    proj_kernel<<<B_ * K_ * (L_ / 64), 512, 0, stream>>>(
        x, ws_xT, ws_Wt, dpw, dpb, ws_r, ws_Bm, ws_Cm);
    scan_kernel<<<B_ * K_ * C_, 256, 0, stream>>>(
        ws_r, x, ws_xT, ws_Bm, ws_Cm, A_log, Ds, ws_fl, out);
}